// Round 2
// baseline (74.144 us; speedup 1.0000x reference)
//
#include <hip/hip_runtime.h>
#include <hip/hip_bf16.h>

// PerspectiveTransformLayer: B=4, H=64, W=64, C=128, N=10 transforms.
// out[b,y,x,c] = sum_n mask[b,n,y,x] * warp_nearest(image[b], t[b,n])[y,x,c] / count
// where count = sum_n mask[b,n,y,x] (0 if count==0).
//
// 32 threads per pixel (each owns a float4 = 4 channels), 8 pixels per
// 256-thread block -> each pixel-group's gather is one coalesced 512B
// transaction. Two-phase inner structure: compute all 10 (offset, weight)
// pairs first, then issue all 10 gathers unconditionally (weight=0 for
// invalid -> branch-free, max memory-level parallelism).

namespace {

constexpr int Bc = 4;
constexpr int Hc = 64;
constexpr int Wc = 64;
constexpr int Cc = 128;
constexpr int Nc = 10;
constexpr int C4 = Cc / 4;          // 32 float4 per pixel
constexpr int PIX_PER_BLOCK = 8;    // 256 threads / 32 threads-per-pixel

__global__ __launch_bounds__(256)
void perspective_warp_avg_kernel(const float* __restrict__ image,
                                 const float* __restrict__ transforms,
                                 const float* __restrict__ mask,
                                 float* __restrict__ out) {
    const int tid = threadIdx.x;
    const int pixInBlock = tid >> 5;   // 0..7
    const int c4 = tid & 31;           // float4 slot within channel dim
    const int pixel = blockIdx.x * PIX_PER_BLOCK + pixInBlock;  // global pixel id
    const int b  = pixel >> 12;        // / (H*W) = / 4096
    const int yx = pixel & 4095;
    const int y  = yx >> 6;
    const int x  = yx & 63;

    // Stage this batch's transforms into LDS, pre-divided by perspective_mul.
    // mul = {1,1,INIT_H/H=4, 1,1,INIT_W/W=4, H/INIT_H=.25, W/INIT_W=.25}
    // division by 4 == *0.25f and by 0.25 == *4.0f exactly (powers of two).
    __shared__ float t_s[Nc * 8];
    if (tid < Nc * 8) {
        const int j = tid & 7;
        const float m = (j == 2 || j == 5) ? 0.25f : ((j >= 6) ? 4.0f : 1.0f);
        t_s[tid] = transforms[b * (Nc * 8) + tid] * m;
    }
    __syncthreads();

    const float fx = (float)x;
    const float fy = (float)y;
    const float4* __restrict__ imgb =
        (const float4*)(image) + (size_t)b * (Hc * Wc * C4);
    const float* __restrict__ maskb = mask + (size_t)(b * Nc) * (Hc * Wc) + y * Wc + x;

    // ---- Phase 1: per-transform address + weight (branch-free) ----
    int   off[Nc];   // float4 offset into imgb for this lane
    float w[Nc];     // mask if valid else 0
    float count = 0.f;

#pragma unroll
    for (int n = 0; n < Nc; ++n) {
        const float t0 = t_s[n * 8 + 0];
        const float t1 = t_s[n * 8 + 1];
        const float t2 = t_s[n * 8 + 2];
        const float t3 = t_s[n * 8 + 3];
        const float t4 = t_s[n * 8 + 4];
        const float t5 = t_s[n * 8 + 5];
        const float t6 = t_s[n * 8 + 6];
        const float t7 = t_s[n * 8 + 7];

        const float denom = t6 * fx + t7 * fy + 1.0f;
        const float xin = (t0 * fx + t1 * fy + t2) / denom;
        const float yin = (t3 * fx + t4 * fy + t5) / denom;

        const bool valid = (xin >= 0.0f) & (xin <= (float)(Wc - 1)) &
                           (yin >= 0.0f) & (yin <= (float)(Hc - 1));

        int xi = (int)floorf(xin + 0.5f);   // round half-up
        int yi = (int)floorf(yin + 0.5f);
        xi = min(max(xi, 0), Wc - 1);
        yi = min(max(yi, 0), Hc - 1);

        const float m = maskb[n * (Hc * Wc)];   // broadcast within group
        count += m;
        w[n]   = valid ? m : 0.0f;              // image finite -> 0*s == 0
        off[n] = (yi * Wc + xi) * C4 + c4;
    }

    // ---- Phase 2: 10 independent gathers, then weighted accumulate ----
    float4 s[Nc];
#pragma unroll
    for (int n = 0; n < Nc; ++n) s[n] = imgb[off[n]];

    float4 acc = make_float4(0.f, 0.f, 0.f, 0.f);
#pragma unroll
    for (int n = 0; n < Nc; ++n) {
        acc.x += w[n] * s[n].x;
        acc.y += w[n] * s[n].y;
        acc.z += w[n] * s[n].z;
        acc.w += w[n] * s[n].w;
    }

    const float inv = (count > 0.f) ? (1.0f / count) : 0.0f;
    // match reference: where(count>0, s/count, 0) — use true divide for safety
    float4 o;
    if (count > 0.f) {
        o = make_float4(acc.x / count, acc.y / count, acc.z / count, acc.w / count);
    } else {
        o = make_float4(0.f, 0.f, 0.f, 0.f);
    }
    (void)inv;
    ((float4*)out)[(size_t)pixel * C4 + c4] = o;
}

}  // namespace

extern "C" void kernel_launch(void* const* d_in, const int* in_sizes, int n_in,
                              void* d_out, int out_size, void* d_ws, size_t ws_size,
                              hipStream_t stream) {
    const float* image      = (const float*)d_in[0];  // (4,64,64,128) f32
    const float* transforms = (const float*)d_in[1];  // (4,10,8) f32
    const float* mask       = (const float*)d_in[2];  // (4,10,64,64) f32
    float* out              = (float*)d_out;          // (4,64,64,128) f32

    const int totalPixels = Bc * Hc * Wc;             // 16384
    const int grid = totalPixels / PIX_PER_BLOCK;     // 2048 blocks
    perspective_warp_avg_kernel<<<grid, 256, 0, stream>>>(image, transforms, mask, out);
}

// Round 4
// 73.266 us; speedup vs baseline: 1.0120x; 1.0120x over previous
//
#include <hip/hip_runtime.h>
#include <hip/hip_bf16.h>

// PerspectiveTransformLayer: B=4, H=64, W=64, C=128, N=10 transforms.
// out[b,y,x,c] = sum_n mask[b,n,y,x] * warp_nearest(image[b], t[b,n])[y,x,c] / count
// count = sum_n mask[b,n,y,x] (0 if count==0).
//
// 32 threads per pixel (each owns a float4 = 4 channels), 8 pixels per
// 256-thread block -> each pixel-group's gather is one coalesced 512B
// transaction. Branch-free two-phase inner loop (all 10 offsets/weights,
// then 10 independent gathers in flight).
//
// R4 = R3 with the compile fix: nontemporal store needs a native clang
// vector type (ext_vector_type), not HIP's float4 class.

namespace {

typedef float f32x4 __attribute__((ext_vector_type(4)));

constexpr int Bc = 4;
constexpr int Hc = 64;
constexpr int Wc = 64;
constexpr int Cc = 128;
constexpr int Nc = 10;
constexpr int C4 = Cc / 4;          // 32 float4 per pixel
constexpr int PIX_PER_BLOCK = 8;    // 256 threads / 32 threads-per-pixel
constexpr int NXCD = 8;

__global__ __launch_bounds__(256)
void perspective_warp_avg_kernel(const float* __restrict__ image,
                                 const float* __restrict__ transforms,
                                 const float* __restrict__ mask,
                                 float* __restrict__ out) {
    // --- XCD-aware swizzle (bijective since gridDim.x = 2048 = 8*256) ---
    // Physical dispatch is round-robin: consecutive blockIdx -> different XCD.
    // Give each XCD a contiguous chunk of the pixel space instead: per-XCD
    // working set = one 2MB image + 0.16MB mask <= 4MB L2.
    const int nblk = gridDim.x;                 // 2048
    const int chunk = nblk / NXCD;              // 256
    const int bid = (int)blockIdx.x;
    const int wg = (bid & (NXCD - 1)) * chunk + (bid >> 3);

    const int tid = threadIdx.x;
    const int pixInBlock = tid >> 5;   // 0..7
    const int c4 = tid & 31;           // float4 slot within channel dim
    const int pixel = wg * PIX_PER_BLOCK + pixInBlock;  // global pixel id
    const int b  = pixel >> 12;        // / (H*W) = / 4096
    const int yx = pixel & 4095;
    const int y  = yx >> 6;
    const int x  = yx & 63;

    // Stage this batch's transforms into LDS, pre-divided by perspective_mul.
    // mul = {1,1,4, 1,1,4, .25,.25}; /4 == *0.25f and /0.25 == *4.0f exactly.
    __shared__ float t_s[Nc * 8];
    if (tid < Nc * 8) {
        const int j = tid & 7;
        const float m = (j == 2 || j == 5) ? 0.25f : ((j >= 6) ? 4.0f : 1.0f);
        t_s[tid] = transforms[b * (Nc * 8) + tid] * m;
    }
    __syncthreads();

    const float fx = (float)x;
    const float fy = (float)y;
    const f32x4* __restrict__ imgb =
        (const f32x4*)(image) + (size_t)b * (Hc * Wc * C4);
    const float* __restrict__ maskb = mask + (size_t)(b * Nc) * (Hc * Wc) + y * Wc + x;

    // ---- Phase 1: per-transform address + weight (branch-free) ----
    int   off[Nc];   // float4 offset into imgb for this lane
    float w[Nc];     // mask if valid else 0
    float count = 0.f;

#pragma unroll
    for (int n = 0; n < Nc; ++n) {
        const float t0 = t_s[n * 8 + 0];
        const float t1 = t_s[n * 8 + 1];
        const float t2 = t_s[n * 8 + 2];
        const float t3 = t_s[n * 8 + 3];
        const float t4 = t_s[n * 8 + 4];
        const float t5 = t_s[n * 8 + 5];
        const float t6 = t_s[n * 8 + 6];
        const float t7 = t_s[n * 8 + 7];

        const float denom = t6 * fx + t7 * fy + 1.0f;
        const float xin = (t0 * fx + t1 * fy + t2) / denom;
        const float yin = (t3 * fx + t4 * fy + t5) / denom;

        const bool valid = (xin >= 0.0f) & (xin <= (float)(Wc - 1)) &
                           (yin >= 0.0f) & (yin <= (float)(Hc - 1));

        int xi = (int)floorf(xin + 0.5f);   // round half-up
        int yi = (int)floorf(yin + 0.5f);
        xi = min(max(xi, 0), Wc - 1);
        yi = min(max(yi, 0), Hc - 1);

        const float m = maskb[n * (Hc * Wc)];   // broadcast within group
        count += m;
        w[n]   = valid ? m : 0.0f;              // image finite -> 0*s == 0
        off[n] = (yi * Wc + xi) * C4 + c4;
    }

    // ---- Phase 2: 10 independent gathers, then weighted accumulate ----
    f32x4 s[Nc];
#pragma unroll
    for (int n = 0; n < Nc; ++n) s[n] = imgb[off[n]];

    f32x4 acc = (f32x4)(0.f);
#pragma unroll
    for (int n = 0; n < Nc; ++n) {
        acc += w[n] * s[n];
    }

    f32x4 o;
    if (count > 0.f) {
        o = acc / count;
    } else {
        o = (f32x4)(0.f);
    }
    // write-once output: nontemporal so it doesn't evict the image from L2
    __builtin_nontemporal_store(o, ((f32x4*)out) + (size_t)pixel * C4 + c4);
}

}  // namespace

extern "C" void kernel_launch(void* const* d_in, const int* in_sizes, int n_in,
                              void* d_out, int out_size, void* d_ws, size_t ws_size,
                              hipStream_t stream) {
    const float* image      = (const float*)d_in[0];  // (4,64,64,128) f32
    const float* transforms = (const float*)d_in[1];  // (4,10,8) f32
    const float* mask       = (const float*)d_in[2];  // (4,10,64,64) f32
    float* out              = (float*)d_out;          // (4,64,64,128) f32

    const int totalPixels = Bc * Hc * Wc;             // 16384
    const int grid = totalPixels / PIX_PER_BLOCK;     // 2048 blocks
    perspective_warp_avg_kernel<<<grid, 256, 0, stream>>>(image, transforms, mask, out);
}

// Round 5
// 70.043 us; speedup vs baseline: 1.0585x; 1.0460x over previous
//
#include <hip/hip_runtime.h>
#include <hip/hip_bf16.h>

// PerspectiveTransformLayer: B=4, H=64, W=64, C=128, N=10 transforms.
// out[b,y,x,c] = sum_n mask[b,n,y,x] * warp_nearest(image[b], t[b,n])[y,x,c] / count
// count = sum_n mask[b,n,y,x] (0 if count==0).
//
// R5: rebalance lanes-per-pixel 32 -> 16 (each thread owns 8 floats = two
// float4 gathers). Halves wave count (8192 -> 4096) and thus the per-wave-
// redundant homography VALU work; gathers stay fully coalesced
// (16 lanes x 32B = 512B). Final normalize via one exact 1/count + multiply
// (final-value rounding only; coordinate divides stay correctly rounded
// because they feed the nearest-neighbor floor decision).
// Kept from R4: XCD-bijective block swizzle, LDS transform table with exact
// power-of-2 perspective_mul rescale, branch-free two-phase loop, NT stores.

namespace {

typedef float f32x4 __attribute__((ext_vector_type(4)));

constexpr int Bc = 4;
constexpr int Hc = 64;
constexpr int Wc = 64;
constexpr int Cc = 128;
constexpr int Nc = 10;
constexpr int C4 = Cc / 4;           // 32 float4 per pixel
constexpr int LANES_PER_PIX = 16;    // each lane owns 2 float4 (8 floats)
constexpr int PIX_PER_BLOCK = 256 / LANES_PER_PIX;  // 16
constexpr int NXCD = 8;

__global__ __launch_bounds__(256)
void perspective_warp_avg_kernel(const float* __restrict__ image,
                                 const float* __restrict__ transforms,
                                 const float* __restrict__ mask,
                                 float* __restrict__ out) {
    // --- XCD-aware swizzle (bijective: gridDim.x = 1024 = 8*128) ---
    const int nblk = gridDim.x;                 // 1024
    const int chunk = nblk / NXCD;              // 128
    const int bid = (int)blockIdx.x;
    const int wg = (bid & (NXCD - 1)) * chunk + (bid >> 3);

    const int tid = threadIdx.x;
    const int pixInBlock = tid >> 4;            // 0..15
    const int c8 = tid & 15;                    // 8-float slot within channels
    const int pixel = wg * PIX_PER_BLOCK + pixInBlock;
    const int b  = pixel >> 12;                 // / 4096
    const int yx = pixel & 4095;
    const int y  = yx >> 6;
    const int x  = yx & 63;

    // Transforms for this batch -> LDS, pre-divided by perspective_mul.
    // mul = {1,1,4, 1,1,4, .25,.25}; /4 == *0.25f and /0.25 == *4.0f exactly.
    __shared__ float t_s[Nc * 8];
    if (tid < Nc * 8) {
        const int j = tid & 7;
        const float m = (j == 2 || j == 5) ? 0.25f : ((j >= 6) ? 4.0f : 1.0f);
        t_s[tid] = transforms[b * (Nc * 8) + tid] * m;
    }
    __syncthreads();

    const float fx = (float)x;
    const float fy = (float)y;
    const f32x4* __restrict__ imgb =
        (const f32x4*)(image) + (size_t)b * (Hc * Wc * C4);
    const float* __restrict__ maskb = mask + (size_t)(b * Nc) * (Hc * Wc) + y * Wc + x;

    // ---- Phase 1: per-transform address + weight (branch-free) ----
    int   off[Nc];   // first float4 offset into imgb for this lane
    float w[Nc];     // mask if valid else 0
    float count = 0.f;

#pragma unroll
    for (int n = 0; n < Nc; ++n) {
        const float t0 = t_s[n * 8 + 0];
        const float t1 = t_s[n * 8 + 1];
        const float t2 = t_s[n * 8 + 2];
        const float t3 = t_s[n * 8 + 3];
        const float t4 = t_s[n * 8 + 4];
        const float t5 = t_s[n * 8 + 5];
        const float t6 = t_s[n * 8 + 6];
        const float t7 = t_s[n * 8 + 7];

        const float denom = t6 * fx + t7 * fy + 1.0f;
        // exact f32 divides: these feed the floor(x+0.5) pixel decision
        const float xin = (t0 * fx + t1 * fy + t2) / denom;
        const float yin = (t3 * fx + t4 * fy + t5) / denom;

        const bool valid = (xin >= 0.0f) & (xin <= (float)(Wc - 1)) &
                           (yin >= 0.0f) & (yin <= (float)(Hc - 1));

        int xi = (int)floorf(xin + 0.5f);   // round half-up
        int yi = (int)floorf(yin + 0.5f);
        xi = min(max(xi, 0), Wc - 1);
        yi = min(max(yi, 0), Hc - 1);

        const float m = maskb[n * (Hc * Wc)];
        count += m;
        w[n]   = valid ? m : 0.0f;              // image finite -> 0*s == 0
        off[n] = (yi * Wc + xi) * C4 + c8 * 2;
    }

    // ---- Phase 2: gathers in two half-batches (10 loads in flight each) ----
    f32x4 a0 = (f32x4)(0.f);
    f32x4 a1 = (f32x4)(0.f);
#pragma unroll
    for (int h = 0; h < 2; ++h) {
        f32x4 s0[5], s1[5];
#pragma unroll
        for (int k = 0; k < 5; ++k) {
            const int n = h * 5 + k;
            s0[k] = imgb[off[n]];
            s1[k] = imgb[off[n] + 1];
        }
#pragma unroll
        for (int k = 0; k < 5; ++k) {
            const int n = h * 5 + k;
            a0 += w[n] * s0[k];
            a1 += w[n] * s1[k];
        }
    }

    // Final normalize: one exact divide, then multiply (<=1ulp vs per-elem
    // divide; no decision boundary downstream). count==0 -> acc==0 -> out 0.
    const float inv = (count > 0.f) ? (1.0f / count) : 0.0f;
    const f32x4 o0 = a0 * inv;
    const f32x4 o1 = a1 * inv;

    f32x4* outp = ((f32x4*)out) + (size_t)pixel * C4 + c8 * 2;
    __builtin_nontemporal_store(o0, outp);
    __builtin_nontemporal_store(o1, outp + 1);
}

}  // namespace

extern "C" void kernel_launch(void* const* d_in, const int* in_sizes, int n_in,
                              void* d_out, int out_size, void* d_ws, size_t ws_size,
                              hipStream_t stream) {
    const float* image      = (const float*)d_in[0];  // (4,64,64,128) f32
    const float* transforms = (const float*)d_in[1];  // (4,10,8) f32
    const float* mask       = (const float*)d_in[2];  // (4,10,64,64) f32
    float* out              = (float*)d_out;          // (4,64,64,128) f32

    const int totalPixels = Bc * Hc * Wc;             // 16384
    const int grid = totalPixels / PIX_PER_BLOCK;     // 1024 blocks
    perspective_warp_avg_kernel<<<grid, 256, 0, stream>>>(image, transforms, mask, out);
}